// Round 4
// baseline (85.874 us; speedup 1.0000x reference)
//
#include <hip/hip_runtime.h>

#define S_LEN 4096
#define BATCH 2
#define DIM 64
#define RAD 128
#define NPOS 257
#define KEXT 4416              // 4096 + 5*64 (rel rows padded)
#define QREL_STR 260
#define PSTR 72                // P LDS row stride in u16 (144B, 16B-aligned)
#define ETS 516                // etile row stride in f32

typedef short s16x8 __attribute__((ext_vector_type(8)));
typedef short s16x4 __attribute__((ext_vector_type(4)));
typedef float f32x4 __attribute__((ext_vector_type(4)));
typedef unsigned short u16;
typedef unsigned int u32;

__device__ __forceinline__ u16 f2bf(float f) {
  union { float f; u32 u; } v; v.f = f;
  u32 u = v.u;
  return (u16)((u + 0x7FFFu + ((u >> 16) & 1u)) >> 16);  // RNE
}

// Kb_ext[b][t][d]: t<4096 -> bf16(K); 4096<=t<4353 -> bf16(rel[t-4096]); else 0
__global__ void prep_k(const float* __restrict__ K, const float* __restrict__ rel,
                       u16* __restrict__ Kb) {
  int b = blockIdx.y;
  int t = blockIdx.x * 4 + (threadIdx.x >> 6);
  int d = threadIdx.x & 63;
  float v = 0.f;
  if (t < S_LEN) v = K[((size_t)b * S_LEN + t) * DIM + d];
  else if (t - S_LEN < NPOS) v = rel[(size_t)(t - S_LEN) * DIM + d];
  Kb[((size_t)b * KEXT + t) * DIM + d] = f2bf(v);
}

// Vt[b][d][t] = bf16(V[b][t][d])
__global__ void prep_v(const float* __restrict__ V, u16* __restrict__ Vt) {
  __shared__ float tile[64][65];
  int b = blockIdx.y;
  int t0 = blockIdx.x * 64;
  for (int i = threadIdx.x; i < 4096; i += 256) {
    int tl = i >> 6, d = i & 63;
    tile[tl][d] = V[((size_t)b * S_LEN + t0 + tl) * DIM + d];
  }
  __syncthreads();
  for (int i = threadIdx.x; i < 4096; i += 256) {
    int d = i >> 6, tl = i & 63;
    Vt[((size_t)b * DIM + d) * S_LEN + t0 + tl] = f2bf(tile[tl][d]);
  }
}

// 16 q-rows per block, 8 waves. Per t-tile of 512 cols, all waves cooperate:
// wave w computes cols [it*512 + w*64, +64) into a block-shared LDS tile,
// then the 16x512 f32 tile is stored ROW-MAJOR: each wave owns 2 full rows,
// 4 back-to-back f32x4 stores = 2KB contiguous per row (DRAM-page friendly).
// Swapped-operand MFMAs keep q == l15 lane-local:
//   QK^T: mfma(kf, qf) -> D[t=q4*4+reg][q=l15]
//   PV:   mfma(vf, pf) -> D[d=dn*16+q4*4+reg][q=l15]
__launch_bounds__(512, 4)
__global__ void attn_main(const float* __restrict__ Q,
                          const u16* __restrict__ Kb,
                          const u16* __restrict__ Vt,
                          float* __restrict__ energy,
                          float* __restrict__ Zout) {
  __shared__ float qrel[16 * QREL_STR];   // 16640 B; [q=l15][p]
  __shared__ u16 plds[8 * 16 * PSTR];     // 18432 B
  __shared__ float etile[16 * ETS];       // 33024 B; [q-row][col in tile]
  // epilogue reuse: etile[(w*16+r)*64+lane]=Zbuf (8192f<=8256f); qrel[0..255]=m,l

  const int tid = threadIdx.x;
  const int lane = tid & 63;
  const int wid = tid >> 6;
  const int l15 = lane & 15, q4 = lane >> 4;
  const int l31 = lane & 31, h = lane >> 5;
  const int bx = blockIdx.x;
  const int b = bx >> 8;
  const int s0 = (bx & 255) * 16;

  const u16* KbB = Kb + (size_t)b * KEXT * DIM;
  const u16* VtB = Vt + (size_t)b * DIM * S_LEN;

  // ---- Q B-fragments (row s0+l15) ----
  s16x8 qfrag[2];
  {
    const float* qp = Q + ((size_t)b * S_LEN + s0 + l15) * DIM + q4 * 8;
#pragma unroll
    for (int ks = 0; ks < 2; ++ks) {
      f32x4 a = *reinterpret_cast<const f32x4*>(qp + ks * 32);
      f32x4 c = *reinterpret_cast<const f32x4*>(qp + ks * 32 + 4);
      s16x8 f;
#pragma unroll
      for (int j = 0; j < 4; ++j) { f[j] = (short)f2bf(a[j]); f[4 + j] = (short)f2bf(c[j]); }
      qfrag[ks] = f;
    }
  }

  const int koff_lane = l15 * DIM + q4 * 8;

  // ---- prologue: Q_rel[p][q] via mfma(rel, q) ----
  if (wid < 5) {
    f32x4 acc[4] = {};
    const u16* kp = KbB + (size_t)(S_LEN + wid * 64) * DIM + koff_lane;
#pragma unroll
    for (int ks = 0; ks < 2; ++ks)
#pragma unroll
      for (int nf = 0; nf < 4; ++nf) {
        s16x8 kf = *reinterpret_cast<const s16x8*>(kp + nf * 16 * DIM + ks * 32);
        acc[nf] = __builtin_amdgcn_mfma_f32_16x16x32_bf16(kf, qfrag[ks], acc[nf], 0, 0, 0);
      }
#pragma unroll
    for (int nf = 0; nf < 4; ++nf)
#pragma unroll
      for (int reg = 0; reg < 4; ++reg) {
        int p = wid * 64 + nf * 16 + q4 * 4 + reg;
        if (p < NPOS) qrel[l15 * QREL_STR + p] = acc[nf][reg];
      }
  }
  __syncthreads();

  // ---- main loop: 8 block-wide t-tiles of 512 ----
  const int qglob = s0 + l15;
  const int qoff = l15 * QREL_STR + RAD;
  u16* pw = plds + wid * 16 * PSTR;
  float* eb = etile + l15 * ETS + wid * 64;     // this wave's compute slice
  float* erow0 = energy + ((size_t)b * S_LEN + s0) * S_LEN;

  float mprev = -INFINITY, lsum = 0.f;
  f32x4 zacc[4] = {};

  for (int it = 0; it < 8; ++it) {
    const int t0 = it * 512 + wid * 64;

    f32x4 acc[4] = {};
    const u16* kp = KbB + (size_t)t0 * DIM + koff_lane;
#pragma unroll
    for (int ks = 0; ks < 2; ++ks)
#pragma unroll
      for (int nf = 0; nf < 4; ++nf) {
        s16x8 kf = *reinterpret_cast<const s16x8*>(kp + nf * 16 * DIM + ks * 32);
        acc[nf] = __builtin_amdgcn_mfma_f32_16x16x32_bf16(kf, qfrag[ks], acc[nf], 0, 0, 0);
      }

    // rel shift + scale; stage into block LDS tile; lane-local max
    float mloc = -INFINITY;
#pragma unroll
    for (int nf = 0; nf < 4; ++nf) {
      const int tb = t0 + nf * 16 + q4 * 4;
#pragma unroll
      for (int reg = 0; reg < 4; ++reg) {
        int p = tb + reg - qglob;
        p = (p < -RAD) ? -RAD : (p > RAD ? RAD : p);
        float e = (acc[nf][reg] + qrel[qoff + p]) * 0.125f;
        acc[nf][reg] = e;
        mloc = fmaxf(mloc, e);
      }
      *reinterpret_cast<f32x4*>(eb + nf * 16 + q4 * 4) = acc[nf];
    }

    mloc = fmaxf(mloc, __shfl_xor(mloc, 16));
    mloc = fmaxf(mloc, __shfl_xor(mloc, 32));
    const float mn = fmaxf(mprev, mloc);
    const float alpha = __expf(mprev - mn);
    mprev = mn;
    lsum *= alpha;
#pragma unroll
    for (int dn = 0; dn < 4; ++dn) zacc[dn] *= alpha;

    float rs = 0.f;
#pragma unroll
    for (int nf = 0; nf < 4; ++nf) {
      s16x4 p4;
#pragma unroll
      for (int reg = 0; reg < 4; ++reg) {
        float pv = __expf(acc[nf][reg] - mn);
        rs += pv;
        p4[reg] = (short)f2bf(pv);
      }
      *reinterpret_cast<s16x4*>(pw + l15 * PSTR + nf * 16 + q4 * 4) = p4;
    }
    rs += __shfl_xor(rs, 16);
    rs += __shfl_xor(rs, 32);
    lsum += rs;

    // PV: mfma(vf, pf) -> zacc[dn] holds Z[d=dn*16+q4*4+reg][q=l15]
#pragma unroll
    for (int ks = 0; ks < 2; ++ks) {
      s16x8 pf = *reinterpret_cast<const s16x8*>(pw + l15 * PSTR + ks * 32 + q4 * 8);
#pragma unroll
      for (int dn = 0; dn < 4; ++dn) {
        s16x8 vf = *reinterpret_cast<const s16x8*>(
            VtB + (size_t)(dn * 16 + l15) * S_LEN + t0 + ks * 32 + q4 * 8);
        zacc[dn] = __builtin_amdgcn_mfma_f32_16x16x32_bf16(vf, pf, zacc[dn], 0, 0, 0);
      }
    }

    // ---- block-wide store phase: 2 full rows per wave, 2KB runs ----
    __syncthreads();
    {
      const int r = wid * 2 + h;
      float* dst = erow0 + (size_t)r * S_LEN + it * 512;
      const float* src = etile + r * ETS;
#pragma unroll
      for (int c = 0; c < 4; ++c) {
        f32x4 v = *reinterpret_cast<const f32x4*>(src + c * 128 + l31 * 4);
        __builtin_nontemporal_store(v, reinterpret_cast<f32x4*>(dst + c * 128 + l31 * 4));
      }
    }
    __syncthreads();
  }

  // ---- cross-wave combine (reuse etile as Zbuf, qrel[0..255] as m/l) ----
#pragma unroll
  for (int dn = 0; dn < 4; ++dn)
    *reinterpret_cast<f32x4*>(&etile[(wid * 16 + l15) * 64 + dn * 16 + q4 * 4]) = zacc[dn];
  if (q4 == 0) {
    qrel[wid * 16 + l15] = mprev;
    qrel[128 + wid * 16 + l15] = lsum;
  }
  __syncthreads();

#pragma unroll
  for (int rr = 0; rr < 2; ++rr) {
    const int r = wid + rr * 8;
    float mf = -INFINITY;
#pragma unroll
    for (int w = 0; w < 8; ++w) mf = fmaxf(mf, qrel[w * 16 + r]);
    float lf = 0.f, z = 0.f;
#pragma unroll
    for (int w = 0; w < 8; ++w) {
      const float sc = __expf(qrel[w * 16 + r] - mf);
      lf += qrel[128 + w * 16 + r] * sc;
      z  += etile[(w * 16 + r) * 64 + lane] * sc;
    }
    Zout[((size_t)b * S_LEN + s0 + r) * DIM + lane] = z / lf;
  }
}

extern "C" void kernel_launch(void* const* d_in, const int* in_sizes, int n_in,
                              void* d_out, int out_size, void* d_ws, size_t ws_size,
                              hipStream_t stream) {
  const float* Q   = (const float*)d_in[0];
  const float* K   = (const float*)d_in[1];
  const float* V   = (const float*)d_in[2];
  const float* rel = (const float*)d_in[3];
  // d_in[4] = segment_ids (unused, segmented=False)

  u16* Kb = (u16*)d_ws;                                   // [B][KEXT][64] bf16
  u16* Vt = Kb + (size_t)BATCH * KEXT * DIM;              // [B][64][S] bf16

  float* energy = (float*)d_out;                          // [B][S][S]
  float* Zout   = energy + (size_t)BATCH * S_LEN * S_LEN; // [B][S][64]

  prep_k<<<dim3(KEXT / 4, BATCH), 256, 0, stream>>>(K, rel, Kb);
  prep_v<<<dim3(S_LEN / 64, BATCH), 256, 0, stream>>>(V, Vt);
  attn_main<<<dim3(BATCH * (S_LEN / 16)), 512, 0, stream>>>(Q, Kb, Vt, energy, Zout);
}

// Round 5
// 84.061 us; speedup vs baseline: 1.0216x; 1.0216x over previous
//
#include <hip/hip_runtime.h>

#define S_LEN 4096
#define BATCH 2
#define DIM 64
#define RAD 128
#define NPOS 257
#define KEXT 4416              // 4096 + 5*64 (rel rows padded)
#define QREL_STR 260
#define PSTR 72                // P LDS row stride in u16 (144B, 16B-aligned)
#define ETS 516                // etile row stride in f32

typedef short s16x8 __attribute__((ext_vector_type(8)));
typedef short s16x4 __attribute__((ext_vector_type(4)));
typedef float f32x4 __attribute__((ext_vector_type(4)));
typedef unsigned short u16;
typedef unsigned int u32;

__device__ __forceinline__ u16 f2bf(float f) {
  union { float f; u32 u; } v; v.f = f;
  u32 u = v.u;
  return (u16)((u + 0x7FFFu + ((u >> 16) & 1u)) >> 16);  // RNE
}

// Kb_ext[b][t][d]: t<4096 -> bf16(K); 4096<=t<4353 -> bf16(rel[t-4096]); else 0
__global__ void prep_k(const float* __restrict__ K, const float* __restrict__ rel,
                       u16* __restrict__ Kb) {
  int b = blockIdx.y;
  int t = blockIdx.x * 4 + (threadIdx.x >> 6);
  int d = threadIdx.x & 63;
  float v = 0.f;
  if (t < S_LEN) v = K[((size_t)b * S_LEN + t) * DIM + d];
  else if (t - S_LEN < NPOS) v = rel[(size_t)(t - S_LEN) * DIM + d];
  Kb[((size_t)b * KEXT + t) * DIM + d] = f2bf(v);
}

// Vt[b][d][t] = bf16(V[b][t][d])
__global__ void prep_v(const float* __restrict__ V, u16* __restrict__ Vt) {
  __shared__ float tile[64][65];
  int b = blockIdx.y;
  int t0 = blockIdx.x * 64;
  for (int i = threadIdx.x; i < 4096; i += 256) {
    int tl = i >> 6, d = i & 63;
    tile[tl][d] = V[((size_t)b * S_LEN + t0 + tl) * DIM + d];
  }
  __syncthreads();
  for (int i = threadIdx.x; i < 4096; i += 256) {
    int d = i >> 6, tl = i & 63;
    Vt[((size_t)b * DIM + d) * S_LEN + t0 + tl] = f2bf(tile[tl][d]);
  }
}

// 16 q-rows per block, 8 waves, block-wide cooperative 16x512 tiles.
// Column-chunk ROTATION across blocks: block bx processes chunk
// (it + (bx>>3)) & 7 at iteration it, so concurrently-live store addresses
// cover all L2 sets / IC slices instead of camping on ~1/8 of them.
// Swapped-operand MFMAs keep q == l15 lane-local:
//   QK^T: mfma(kf, qf) -> D[t=q4*4+reg][q=l15]
//   PV:   mfma(vf, pf) -> D[d=dn*16+q4*4+reg][q=l15]
__launch_bounds__(512, 4)
__global__ void attn_main(const float* __restrict__ Q,
                          const u16* __restrict__ Kb,
                          const u16* __restrict__ Vt,
                          float* __restrict__ energy,
                          float* __restrict__ Zout) {
  __shared__ float qrel[16 * QREL_STR];   // 16640 B; [q=l15][p]
  __shared__ u16 plds[8 * 16 * PSTR];     // 18432 B
  __shared__ float etile[16 * ETS];       // 33024 B; [q-row][col in tile]
  // epilogue reuse: etile[(w*16+r)*64+lane]=Zbuf; qrel[0..255]=m,l

  const int tid = threadIdx.x;
  const int lane = tid & 63;
  const int wid = tid >> 6;
  const int l15 = lane & 15, q4 = lane >> 4;
  const int l31 = lane & 31, h = lane >> 5;
  const int bx = blockIdx.x;
  const int b = bx >> 8;
  const int s0 = (bx & 255) * 16;
  const int rot = (bx >> 3) & 7;          // per-XCD-population phase rotation

  const u16* KbB = Kb + (size_t)b * KEXT * DIM;
  const u16* VtB = Vt + (size_t)b * DIM * S_LEN;

  // ---- Q B-fragments (row s0+l15) ----
  s16x8 qfrag[2];
  {
    const float* qp = Q + ((size_t)b * S_LEN + s0 + l15) * DIM + q4 * 8;
#pragma unroll
    for (int ks = 0; ks < 2; ++ks) {
      f32x4 a = *reinterpret_cast<const f32x4*>(qp + ks * 32);
      f32x4 c = *reinterpret_cast<const f32x4*>(qp + ks * 32 + 4);
      s16x8 f;
#pragma unroll
      for (int j = 0; j < 4; ++j) { f[j] = (short)f2bf(a[j]); f[4 + j] = (short)f2bf(c[j]); }
      qfrag[ks] = f;
    }
  }

  const int koff_lane = l15 * DIM + q4 * 8;

  // ---- prologue: Q_rel[p][q] via mfma(rel, q) ----
  if (wid < 5) {
    f32x4 acc[4] = {};
    const u16* kp = KbB + (size_t)(S_LEN + wid * 64) * DIM + koff_lane;
#pragma unroll
    for (int ks = 0; ks < 2; ++ks)
#pragma unroll
      for (int nf = 0; nf < 4; ++nf) {
        s16x8 kf = *reinterpret_cast<const s16x8*>(kp + nf * 16 * DIM + ks * 32);
        acc[nf] = __builtin_amdgcn_mfma_f32_16x16x32_bf16(kf, qfrag[ks], acc[nf], 0, 0, 0);
      }
#pragma unroll
    for (int nf = 0; nf < 4; ++nf)
#pragma unroll
      for (int reg = 0; reg < 4; ++reg) {
        int p = wid * 64 + nf * 16 + q4 * 4 + reg;
        if (p < NPOS) qrel[l15 * QREL_STR + p] = acc[nf][reg];
      }
  }
  __syncthreads();

  // ---- main loop: 8 block-wide t-tiles of 512, rotated per block ----
  const int qglob = s0 + l15;
  const int qoff = l15 * QREL_STR + RAD;
  u16* pw = plds + wid * 16 * PSTR;
  float* eb = etile + l15 * ETS + wid * 64;     // this wave's compute slice
  float* erow0 = energy + ((size_t)b * S_LEN + s0) * S_LEN;

  float mprev = -INFINITY, lsum = 0.f;
  f32x4 zacc[4] = {};

  for (int it = 0; it < 8; ++it) {
    const int itc = (it + rot) & 7;             // this block's column chunk
    const int t0 = itc * 512 + wid * 64;

    f32x4 acc[4] = {};
    const u16* kp = KbB + (size_t)t0 * DIM + koff_lane;
#pragma unroll
    for (int ks = 0; ks < 2; ++ks)
#pragma unroll
      for (int nf = 0; nf < 4; ++nf) {
        s16x8 kf = *reinterpret_cast<const s16x8*>(kp + nf * 16 * DIM + ks * 32);
        acc[nf] = __builtin_amdgcn_mfma_f32_16x16x32_bf16(kf, qfrag[ks], acc[nf], 0, 0, 0);
      }

    // rel shift + scale; stage into block LDS tile; lane-local max
    float mloc = -INFINITY;
#pragma unroll
    for (int nf = 0; nf < 4; ++nf) {
      const int tb = t0 + nf * 16 + q4 * 4;
#pragma unroll
      for (int reg = 0; reg < 4; ++reg) {
        int p = tb + reg - qglob;
        p = (p < -RAD) ? -RAD : (p > RAD ? RAD : p);
        float e = (acc[nf][reg] + qrel[qoff + p]) * 0.125f;
        acc[nf][reg] = e;
        mloc = fmaxf(mloc, e);
      }
      *reinterpret_cast<f32x4*>(eb + nf * 16 + q4 * 4) = acc[nf];
    }

    mloc = fmaxf(mloc, __shfl_xor(mloc, 16));
    mloc = fmaxf(mloc, __shfl_xor(mloc, 32));
    const float mn = fmaxf(mprev, mloc);
    const float alpha = __expf(mprev - mn);
    mprev = mn;
    lsum *= alpha;
#pragma unroll
    for (int dn = 0; dn < 4; ++dn) zacc[dn] *= alpha;

    float rs = 0.f;
#pragma unroll
    for (int nf = 0; nf < 4; ++nf) {
      s16x4 p4;
#pragma unroll
      for (int reg = 0; reg < 4; ++reg) {
        float pv = __expf(acc[nf][reg] - mn);
        rs += pv;
        p4[reg] = (short)f2bf(pv);
      }
      *reinterpret_cast<s16x4*>(pw + l15 * PSTR + nf * 16 + q4 * 4) = p4;
    }
    rs += __shfl_xor(rs, 16);
    rs += __shfl_xor(rs, 32);
    lsum += rs;

    // PV: mfma(vf, pf) -> zacc[dn] holds Z[d=dn*16+q4*4+reg][q=l15]
#pragma unroll
    for (int ks = 0; ks < 2; ++ks) {
      s16x8 pf = *reinterpret_cast<const s16x8*>(pw + l15 * PSTR + ks * 32 + q4 * 8);
#pragma unroll
      for (int dn = 0; dn < 4; ++dn) {
        s16x8 vf = *reinterpret_cast<const s16x8*>(
            VtB + (size_t)(dn * 16 + l15) * S_LEN + t0 + ks * 32 + q4 * 8);
        zacc[dn] = __builtin_amdgcn_mfma_f32_16x16x32_bf16(vf, pf, zacc[dn], 0, 0, 0);
      }
    }

    // ---- block-wide store phase: 2 full rows per wave, 2KB runs ----
    __syncthreads();
    {
      const int r = wid * 2 + h;
      float* dst = erow0 + (size_t)r * S_LEN + itc * 512;
      const float* src = etile + r * ETS;
#pragma unroll
      for (int c = 0; c < 4; ++c) {
        f32x4 v = *reinterpret_cast<const f32x4*>(src + c * 128 + l31 * 4);
        __builtin_nontemporal_store(v, reinterpret_cast<f32x4*>(dst + c * 128 + l31 * 4));
      }
    }
    __syncthreads();
  }

  // ---- cross-wave combine (reuse etile as Zbuf, qrel[0..255] as m/l) ----
#pragma unroll
  for (int dn = 0; dn < 4; ++dn)
    *reinterpret_cast<f32x4*>(&etile[(wid * 16 + l15) * 64 + dn * 16 + q4 * 4]) = zacc[dn];
  if (q4 == 0) {
    qrel[wid * 16 + l15] = mprev;
    qrel[128 + wid * 16 + l15] = lsum;
  }
  __syncthreads();

#pragma unroll
  for (int rr = 0; rr < 2; ++rr) {
    const int r = wid + rr * 8;
    float mf = -INFINITY;
#pragma unroll
    for (int w = 0; w < 8; ++w) mf = fmaxf(mf, qrel[w * 16 + r]);
    float lf = 0.f, z = 0.f;
#pragma unroll
    for (int w = 0; w < 8; ++w) {
      const float sc = __expf(qrel[w * 16 + r] - mf);
      lf += qrel[128 + w * 16 + r] * sc;
      z  += etile[(w * 16 + r) * 64 + lane] * sc;
    }
    Zout[((size_t)b * S_LEN + s0 + r) * DIM + lane] = z / lf;
  }
}

extern "C" void kernel_launch(void* const* d_in, const int* in_sizes, int n_in,
                              void* d_out, int out_size, void* d_ws, size_t ws_size,
                              hipStream_t stream) {
  const float* Q   = (const float*)d_in[0];
  const float* K   = (const float*)d_in[1];
  const float* V   = (const float*)d_in[2];
  const float* rel = (const float*)d_in[3];
  // d_in[4] = segment_ids (unused, segmented=False)

  u16* Kb = (u16*)d_ws;                                   // [B][KEXT][64] bf16
  u16* Vt = Kb + (size_t)BATCH * KEXT * DIM;              // [B][64][S] bf16

  float* energy = (float*)d_out;                          // [B][S][S]
  float* Zout   = energy + (size_t)BATCH * S_LEN * S_LEN; // [B][S][64]

  prep_k<<<dim3(KEXT / 4, BATCH), 256, 0, stream>>>(K, rel, Kb);
  prep_v<<<dim3(S_LEN / 64, BATCH), 256, 0, stream>>>(V, Vt);
  attn_main<<<dim3(BATCH * (S_LEN / 16)), 512, 0, stream>>>(Q, Kb, Vt, energy, Zout);
}